// Round 1
// baseline (10945.921 us; speedup 1.0000x reference)
//
#include <hip/hip_runtime.h>
#include <cmath>
#include <climits>

#define N_ 2048
#define T_ 4096
#define MAXSP 256

// jax.nn.softplus(x) = logaddexp(x, 0) = max(x,0) + log1p(exp(-|x|))
__device__ __forceinline__ float softplus_f(float x) {
    return fmaxf(x, 0.0f) + log1pf(expf(-fabsf(x)));
}

// Fill tevents/yevents with +inf, event_types with 0 (defaults for
// never-written spike slots). The scan kernel overwrites slots [0, cnt).
__global__ void snn_init_tail(float* __restrict__ out) {
    const size_t base    = (size_t)T_ * N_ * 3;                    // after ys
    const size_t inf_cnt = (size_t)MAXSP + (size_t)MAXSP * N_ * 3; // tev + yev
    const size_t tot     = inf_cnt + (size_t)MAXSP * N_;           // + et
    size_t idx = (size_t)blockIdx.x * blockDim.x + threadIdx.x;
    if (idx < tot) {
        out[base + idx] = (idx < inf_cnt) ? __builtin_inff() : 0.0f;
    }
}

// Single persistent workgroup: 1024 threads, 2 neurons per thread
// (n0 = tid, n1 = tid + 1024). State (v, i, s) lives in registers.
// Per step: elementwise Euler update, block-wide min-index reduction over
// the spike mask (argmax of bool = first true index), then the uniform
// event branch (w-row read, resets, spike-record writes).
extern "C" __global__ void __launch_bounds__(1024)
snn_scan(const float* __restrict__ w,   const float* __restrict__ mu,
         const float* __restrict__ v0,  const float* __restrict__ i0,
         const float* __restrict__ ic,  const float* __restrict__ u_init,
         const float* __restrict__ u_re, float* __restrict__ out)
{
#pragma clang fp contract(off)
    const int tid = threadIdx.x;
    const int n0 = tid, n1 = tid + 1024;
    const float dt = 1.0f / 4096.0f;   // exact: 2^-12
    const float mu1 = mu[0], mu2 = mu[1];

    float* ys  = out;
    float* tev = out + (size_t)T_ * N_ * 3;
    float* yev = tev + MAXSP;
    float* et  = yev + (size_t)MAXSP * N_ * 3;
    float* nsp = et  + (size_t)MAXSP * N_;

    float v[2], ii[2], ss[2];
    v[0]  = v0[n0];  v[1]  = v0[n1];
    ii[0] = i0[n0];  ii[1] = i0[n1];
    ss[0] = logf(u_init[n0]) - 0.01f;
    ss[1] = logf(u_init[n1]) - 0.01f;

    __shared__ int red[16];
    __shared__ int s_eidx;

    // software-pipelined ic load (next step prefetched during current)
    float icc0 = ic[n0], icc1 = ic[n1];

    int cnt = 0;
    for (int t = 0; t < T_; ++t) {
        float nic0 = 0.0f, nic1 = 0.0f;
        if (t + 1 < T_) {
            const float* icn = ic + (size_t)(t + 1) * N_;
            nic0 = icn[n0]; nic1 = icn[n1];
        }

        // Euler step — op order matches reference exactly (no FMA contraction):
        // v1 = v + dt*(mu1*((i + ic) - v)); i1 = i + dt*((-mu2)*i);
        // s1 = s + dt*softplus(v_old)
        float v1_0 = v[0] + dt * (mu1 * ((ii[0] + icc0) - v[0]));
        float v1_1 = v[1] + dt * (mu1 * ((ii[1] + icc1) - v[1]));
        float i1_0 = ii[0] + dt * ((-mu2) * ii[0]);
        float i1_1 = ii[1] + dt * ((-mu2) * ii[1]);
        float s1_0 = ss[0] + dt * softplus_f(v[0]);
        float s1_1 = ss[1] + dt * softplus_f(v[1]);

        bool m0 = (s1_0 >= 0.0f), m1 = (s1_1 >= 0.0f);

        // block-wide min-index over masked neurons (argmax of bool mask)
        int cand = m0 ? n0 : (m1 ? n1 : INT_MAX);
        int x = cand;
        #pragma unroll
        for (int off = 32; off > 0; off >>= 1) {
            int y = __shfl_down(x, off);
            x = (y < x) ? y : x;
        }
        if ((tid & 63) == 0) red[tid >> 6] = x;
        __syncthreads();
        if (tid < 64) {
            int z = (tid < 16) ? red[tid] : INT_MAX;
            #pragma unroll
            for (int off = 8; off > 0; off >>= 1) {
                int y = __shfl_down(z, off);
                z = (y < z) ? y : z;
            }
            if (tid == 0) s_eidx = z;
        }
        __syncthreads();
        const int eidx = s_eidx;          // uniform across block

        if (eidx != INT_MAX) {            // event step (uniform branch)
            const float* wrow = w + (size_t)eidx * N_;
            float w0 = wrow[n0], w1 = wrow[n1];
            const float* ut = u_re + (size_t)t * N_;

            float v2_0 = v1_0, v2_1 = v1_1;
            float s2_0 = s1_0, s2_1 = s1_1;
            if (m0) { v2_0 = v1_0 - 1.0f; s2_0 = logf(ut[n0]) - 0.01f; }
            if (m1) { v2_1 = v1_1 - 1.0f; s2_1 = logf(ut[n1]) - 0.01f; }
            float i2_0 = i1_0 + w0;       // w-row added to ALL neurons
            float i2_1 = i1_1 + w1;

            if (cnt < MAXSP) {            // record spike (pre-transition state)
                if (tid == 0) tev[cnt] = (float)(t + 1) * dt;
                float* ye = yev + (size_t)cnt * N_ * 3;
                ye[n0 * 3 + 0] = v1_0; ye[n0 * 3 + 1] = i1_0; ye[n0 * 3 + 2] = s1_0;
                ye[n1 * 3 + 0] = v1_1; ye[n1 * 3 + 1] = i1_1; ye[n1 * 3 + 2] = s1_1;
                float* ee = et + (size_t)cnt * N_;
                ee[n0] = m0 ? 1.0f : 0.0f;
                ee[n1] = m1 ? 1.0f : 0.0f;
                cnt++;
            }
            v[0] = v2_0; v[1] = v2_1;
            ii[0] = i2_0; ii[1] = i2_1;
            ss[0] = s2_0; ss[1] = s2_1;
        } else {
            v[0] = v1_0; v[1] = v1_1;
            ii[0] = i1_0; ii[1] = i1_1;
            ss[0] = s1_0; ss[1] = s1_1;
        }

        // ys[t] = post-transition state (y_new)
        float* yr = ys + (size_t)t * N_ * 3;
        yr[n0 * 3 + 0] = v[0];  yr[n0 * 3 + 1] = ii[0]; yr[n0 * 3 + 2] = ss[0];
        yr[n1 * 3 + 0] = v[1];  yr[n1 * 3 + 1] = ii[1]; yr[n1 * 3 + 2] = ss[1];

        icc0 = nic0; icc1 = nic1;
    }

    if (tid == 0) nsp[0] = (float)cnt;
}

extern "C" void kernel_launch(void* const* d_in, const int* in_sizes, int n_in,
                              void* d_out, int out_size, void* d_ws, size_t ws_size,
                              hipStream_t stream) {
    const float* w      = (const float*)d_in[0];
    const float* mu     = (const float*)d_in[1];
    const float* v0     = (const float*)d_in[2];
    const float* i0     = (const float*)d_in[3];
    const float* ic     = (const float*)d_in[4];
    const float* u_init = (const float*)d_in[5];
    const float* u_re   = (const float*)d_in[6];
    float* out = (float*)d_out;

    // fill spike-record tails with defaults (inf / inf / 0)
    const size_t tail = (size_t)MAXSP + (size_t)MAXSP * N_ * 3 + (size_t)MAXSP * N_;
    int blocks = (int)((tail + 255) / 256);
    snn_init_tail<<<blocks, 256, 0, stream>>>(out);

    // sequential scan: one persistent workgroup
    snn_scan<<<1, 1024, 0, stream>>>(w, mu, v0, i0, ic, u_init, u_re, out);
}

// Round 2
// 5122.930 us; speedup vs baseline: 2.1367x; 2.1367x over previous
//
#include <hip/hip_runtime.h>
#include <cmath>
#include <climits>

#define N_ 2048
#define T_ 4096
#define MAXSP 256

// Fill tevents/yevents with +inf, event_types with 0 (defaults for
// never-written spike slots). The scan kernel overwrites slots [0, cnt).
__global__ void snn_init_tail(float* __restrict__ out) {
    const size_t base    = (size_t)T_ * N_ * 3;                    // after ys
    const size_t inf_cnt = (size_t)MAXSP + (size_t)MAXSP * N_ * 3; // tev + yev
    const size_t tot     = inf_cnt + (size_t)MAXSP * N_;           // + et
    size_t idx = (size_t)blockIdx.x * blockDim.x + threadIdx.x;
    if (idx < tot) {
        out[base + idx] = (idx < inf_cnt) ? __builtin_inff() : 0.0f;
    }
}

// Single persistent workgroup: 1024 threads, 2 neurons per thread.
// VALU-throughput-bound on one CU -> use hw transcendentals (v_exp/v_log),
// one barrier per step (ballot candidates + double-buffered LDS + redundant
// per-wave shfl reduce), running pointers, unconditional u_re prefetch.
extern "C" __global__ void __launch_bounds__(1024)
snn_scan(const float* __restrict__ w,   const float* __restrict__ mu,
         const float* __restrict__ v0,  const float* __restrict__ i0,
         const float* __restrict__ ic,  const float* __restrict__ u_init,
         const float* __restrict__ u_re, float* __restrict__ out)
{
#pragma clang fp contract(off)
    const int tid  = threadIdx.x;
    const int n0   = tid, n1 = tid + 1024;
    const int wv   = tid >> 6, lane = tid & 63;
    const float dt = 1.0f / 4096.0f;   // exact: 2^-12
    const float mu1 = mu[0], mu2 = mu[1];

    float* ys  = out;
    float* tev = out + (size_t)T_ * N_ * 3;
    float* yev = tev + MAXSP;
    float* et  = yev + (size_t)MAXSP * N_ * 3;
    float* nsp = et  + (size_t)MAXSP * N_;

    float v[2], ii[2], ss[2];
    v[0]  = v0[n0];  v[1]  = v0[n1];
    ii[0] = i0[n0];  ii[1] = i0[n1];
    ss[0] = logf(u_init[n0]) - 0.01f;   // one-time: keep precise
    ss[1] = logf(u_init[n1]) - 0.01f;

    __shared__ int red[2][16];          // double-buffered -> 1 barrier/step

    // running per-thread pointers (kill per-step 64-bit addr recompute)
    const float* icp0 = ic + n0 + N_;   // points at ic[t+1]
    const float* icp1 = ic + n1 + N_;
    const float* up0  = u_re + n0;      // points at u_re[t]
    const float* up1  = u_re + n1;
    float* yr0 = ys + (size_t)n0 * 3;
    float* yr1 = ys + (size_t)n1 * 3;

    float icc0 = ic[n0], icc1 = ic[n1]; // ic[0] preloaded

    int cnt = 0;
    for (int t = 0; t < T_; ++t) {
        // prefetch: u_re[t] (maybe needed post-reduction) and ic[t+1]
        float u0 = up0[0], u1 = up1[0];
        float nic0 = 0.0f, nic1 = 0.0f;
        if (t + 1 < T_) { nic0 = icp0[0]; nic1 = icp1[0]; }

        // Euler step — op order matches reference (no FMA contraction):
        float v1_0 = v[0] + dt * (mu1 * ((ii[0] + icc0) - v[0]));
        float v1_1 = v[1] + dt * (mu1 * ((ii[1] + icc1) - v[1]));
        float i1_0 = ii[0] + dt * ((-mu2) * ii[0]);
        float i1_1 = ii[1] + dt * ((-mu2) * ii[1]);
        // softplus via hw v_exp/v_log: max(x,0) + log(1 + exp(-|x|))
        float sp0 = fmaxf(v[0], 0.0f) + __logf(1.0f + __expf(-fabsf(v[0])));
        float sp1 = fmaxf(v[1], 0.0f) + __logf(1.0f + __expf(-fabsf(v[1])));
        float s1_0 = ss[0] + dt * sp0;
        float s1_1 = ss[1] + dt * sp1;

        bool m0 = (s1_0 >= 0.0f), m1 = (s1_1 >= 0.0f);

        // per-wave first-masked-index candidate (scalar ballot + ffs)
        unsigned long long b0 = __ballot(m0);
        unsigned long long b1 = __ballot(m1);
        int cand = INT_MAX;
        const int wbase = wv << 6;
        if (b0)      cand = wbase + (__ffsll((long long)b0) - 1);
        else if (b1) cand = 1024 + wbase + (__ffsll((long long)b1) - 1);

        const int par = t & 1;
        if (lane == 0) red[par][wv] = cand;
        __syncthreads();
        // all waves redundantly reduce the 16 candidates (no 2nd barrier)
        int x = red[par][lane & 15];
        #pragma unroll
        for (int off = 1; off < 16; off <<= 1) {
            int y = __shfl_xor(x, off);
            x = (y < x) ? y : x;
        }
        const int eidx = x;               // uniform across block

        if (eidx != INT_MAX) {            // event step (uniform branch)
            const float* wrow = w + (size_t)eidx * N_;
            float w0 = wrow[n0], w1 = wrow[n1];

            float i2_0 = i1_0 + w0;       // w-row added to ALL neurons
            float i2_1 = i1_1 + w1;
            float v2_0 = m0 ? (v1_0 - 1.0f) : v1_0;
            float v2_1 = m1 ? (v1_1 - 1.0f) : v1_1;
            float s2_0 = m0 ? (__logf(u0) - 0.01f) : s1_0;
            float s2_1 = m1 ? (__logf(u1) - 0.01f) : s1_1;

            if (cnt < MAXSP) {            // record spike (pre-transition y)
                if (tid == 0) tev[cnt] = (float)(t + 1) * dt;
                float* ye = yev + (size_t)cnt * N_ * 3;
                ye[n0 * 3 + 0] = v1_0; ye[n0 * 3 + 1] = i1_0; ye[n0 * 3 + 2] = s1_0;
                ye[n1 * 3 + 0] = v1_1; ye[n1 * 3 + 1] = i1_1; ye[n1 * 3 + 2] = s1_1;
                float* ee = et + (size_t)cnt * N_;
                ee[n0] = m0 ? 1.0f : 0.0f;
                ee[n1] = m1 ? 1.0f : 0.0f;
                cnt++;
            }
            v[0] = v2_0; v[1] = v2_1;
            ii[0] = i2_0; ii[1] = i2_1;
            ss[0] = s2_0; ss[1] = s2_1;
        } else {
            v[0] = v1_0; v[1] = v1_1;
            ii[0] = i1_0; ii[1] = i1_1;
            ss[0] = s1_0; ss[1] = s1_1;
        }

        // ys[t] = post-transition state
        yr0[0] = v[0];  yr0[1] = ii[0]; yr0[2] = ss[0];
        yr1[0] = v[1];  yr1[1] = ii[1]; yr1[2] = ss[1];

        icc0 = nic0; icc1 = nic1;
        icp0 += N_; icp1 += N_;
        up0  += N_; up1  += N_;
        yr0  += (size_t)3 * N_; yr1 += (size_t)3 * N_;
    }

    if (tid == 0) nsp[0] = (float)cnt;
}

extern "C" void kernel_launch(void* const* d_in, const int* in_sizes, int n_in,
                              void* d_out, int out_size, void* d_ws, size_t ws_size,
                              hipStream_t stream) {
    const float* w      = (const float*)d_in[0];
    const float* mu     = (const float*)d_in[1];
    const float* v0     = (const float*)d_in[2];
    const float* i0     = (const float*)d_in[3];
    const float* ic     = (const float*)d_in[4];
    const float* u_init = (const float*)d_in[5];
    const float* u_re   = (const float*)d_in[6];
    float* out = (float*)d_out;

    const size_t tail = (size_t)MAXSP + (size_t)MAXSP * N_ * 3 + (size_t)MAXSP * N_;
    int blocks = (int)((tail + 255) / 256);
    snn_init_tail<<<blocks, 256, 0, stream>>>(out);

    snn_scan<<<1, 1024, 0, stream>>>(w, mu, v0, i0, ic, u_init, u_re, out);
}

// Round 3
// 4309.320 us; speedup vs baseline: 2.5401x; 1.1888x over previous
//
#include <hip/hip_runtime.h>
#include <cmath>
#include <climits>

#define N_ 2048
#define T_ 4096
#define MAXSP 256
#define CHUNK 256
#define NCHUNK (T_ / CHUNK)   // 16

// ---------------- workspace layout (d_ws) ----------------
// int   eidx[T_]                  : per-step event neuron index, -1 = none
// int   cnt_at[NCHUNK]            : saturating spike count at chunk start
// float snap[NCHUNK][3][N_]       : (v, i, s) planes at chunk start
#define WS_EIDX_OFF   0
#define WS_CNT_OFF    (T_ * 4)
#define WS_SNAP_OFF   (T_ * 4 + NCHUNK * 4)

__device__ __forceinline__ int imin(int a, int b) { return a < b ? a : b; }

// Fill tevents/yevents with +inf, event_types with 0 (defaults for
// never-written spike slots). Replay overwrites slots [0, cnt_total).
__global__ void snn_init_tail(float* __restrict__ out) {
    const size_t base    = (size_t)T_ * N_ * 3;                    // after ys
    const size_t inf_cnt = (size_t)MAXSP + (size_t)MAXSP * N_ * 3; // tev + yev
    const size_t tot     = inf_cnt + (size_t)MAXSP * N_;           // + et
    size_t idx = (size_t)blockIdx.x * blockDim.x + threadIdx.x;
    if (idx < tot) {
        out[base + idx] = (idx < inf_cnt) ? __builtin_inff() : 0.0f;
    }
}

// ---------------- Kernel A: sequential scan (1 WG) ----------------
// Computes the coupled dynamics; emits ONLY the event schedule, chunk
// snapshots, tevents and num_spikes. No bulk ys/yev/et traffic.
extern "C" __global__ void __launch_bounds__(1024)
snn_scan(const float* __restrict__ w,   const float* __restrict__ mu,
         const float* __restrict__ v0,  const float* __restrict__ i0,
         const float* __restrict__ ic,  const float* __restrict__ u_init,
         const float* __restrict__ u_re, float* __restrict__ out,
         int* __restrict__ ws_eidx, int* __restrict__ ws_cnt,
         float* __restrict__ ws_snap)
{
#pragma clang fp contract(off)
    const int tid  = threadIdx.x;
    const int n0   = tid * 2;            // two ADJACENT neurons -> float2 loads
    const int wv   = tid >> 6, lane = tid & 63;
    const float dt = 1.0f / 4096.0f;     // exact: 2^-12
    const float mu1 = mu[0], mu2 = mu[1];

    float* tev = out + (size_t)T_ * N_ * 3;
    float* nsp = tev + MAXSP + (size_t)MAXSP * N_ * 3 + (size_t)MAXSP * N_;

    float v[2], ii[2], ss[2];
    { float2 a = *(const float2*)(v0 + n0); v[0] = a.x; v[1] = a.y; }
    { float2 a = *(const float2*)(i0 + n0); ii[0] = a.x; ii[1] = a.y; }
    { float2 a = *(const float2*)(u_init + n0);
      ss[0] = logf(a.x) - 0.01f; ss[1] = logf(a.y) - 0.01f; }  // one-time precise

    __shared__ __align__(16) int red[2][16];

    const float* icp = ic + n0 + N_;     // -> ic[t+1]
    const float* up  = u_re + n0;        // -> u_re[t]
    float2 icc = *(const float2*)(ic + n0);

    int cnt = 0;
    for (int t = 0; t < T_; ++t) {
        // chunk snapshot (state BEFORE step t) + chunk-start count
        if ((t & (CHUNK - 1)) == 0) {
            const int c = t >> 8;
            float* sp = ws_snap + (size_t)c * 3 * N_;
            *(float2*)(sp + n0)          = make_float2(v[0], v[1]);
            *(float2*)(sp + N_ + n0)     = make_float2(ii[0], ii[1]);
            *(float2*)(sp + 2 * N_ + n0) = make_float2(ss[0], ss[1]);
            if (tid == 0) ws_cnt[c] = cnt;
        }

        float2 u2 = *(const float2*)up;                 // prefetch u_re[t]
        float2 nic = make_float2(0.0f, 0.0f);
        if (t + 1 < T_) nic = *(const float2*)icp;      // prefetch ic[t+1]

        // Euler step — op order matches reference (no FMA contraction)
        float v1_0 = v[0] + dt * (mu1 * ((ii[0] + icc.x) - v[0]));
        float v1_1 = v[1] + dt * (mu1 * ((ii[1] + icc.y) - v[1]));
        float i1_0 = ii[0] + dt * ((-mu2) * ii[0]);
        float i1_1 = ii[1] + dt * ((-mu2) * ii[1]);
        float sp0 = fmaxf(v[0], 0.0f) + __logf(1.0f + __expf(-fabsf(v[0])));
        float sp1 = fmaxf(v[1], 0.0f) + __logf(1.0f + __expf(-fabsf(v[1])));
        float s1_0 = ss[0] + dt * sp0;
        float s1_1 = ss[1] + dt * sp1;

        bool m0 = (s1_0 >= 0.0f), m1 = (s1_1 >= 0.0f);

        // per-wave first-spiking-neuron candidate (neurons increase with lane)
        unsigned long long b0 = __ballot(m0);
        unsigned long long b1 = __ballot(m1);
        const int wbase = wv << 7;   // 128 neurons per wave
        int c0 = b0 ? (wbase + ((__ffsll((long long)b0) - 1) << 1))     : INT_MAX;
        int c1 = b1 ? (wbase + ((__ffsll((long long)b1) - 1) << 1) + 1) : INT_MAX;
        int cand = imin(c0, c1);

        const int par = t & 1;
        if (lane == 0) red[par][wv] = cand;
        __syncthreads();
        // broadcast-read all 16 candidates, register min-tree (no shfl chain)
        const int4* r4 = (const int4*)red[par];
        int4 a4 = r4[0], b4 = r4[1], c4 = r4[2], d4 = r4[3];
        int e01 = imin(imin(a4.x, a4.y), imin(a4.z, a4.w));
        int e23 = imin(imin(b4.x, b4.y), imin(b4.z, b4.w));
        int e45 = imin(imin(c4.x, c4.y), imin(c4.z, c4.w));
        int e67 = imin(imin(d4.x, d4.y), imin(d4.z, d4.w));
        const int eidx = imin(imin(e01, e23), imin(e45, e67));

        if (tid == 0) ws_eidx[t] = (eidx == INT_MAX) ? -1 : eidx;

        if (eidx != INT_MAX) {            // event step (uniform branch)
            float2 w2 = *(const float2*)(w + (size_t)eidx * N_ + n0);
            float i2_0 = i1_0 + w2.x;     // w-row added to ALL neurons
            float i2_1 = i1_1 + w2.y;
            float v2_0 = m0 ? (v1_0 - 1.0f) : v1_0;
            float v2_1 = m1 ? (v1_1 - 1.0f) : v1_1;
            float s2_0 = m0 ? (__logf(u2.x) - 0.01f) : s1_0;
            float s2_1 = m1 ? (__logf(u2.y) - 0.01f) : s1_1;
            if (cnt < MAXSP) {
                if (tid == 0) tev[cnt] = (float)(t + 1) * dt;
                cnt++;
            }
            v[0] = v2_0; v[1] = v2_1;
            ii[0] = i2_0; ii[1] = i2_1;
            ss[0] = s2_0; ss[1] = s2_1;
        } else {
            v[0] = v1_0; v[1] = v1_1;
            ii[0] = i1_0; ii[1] = i1_1;
            ss[0] = s1_0; ss[1] = s1_1;
        }

        icc = nic;
        icp += N_; up += N_;
    }

    if (tid == 0) nsp[0] = (float)cnt;
}

// ---------------- Kernel B: parallel replay ----------------
// Grid = NCHUNK chunks x 8 blocks of 256 neurons. Each thread replays one
// neuron over one 256-step chunk, bit-identically to the scan, and streams
// ys / yev / et at multi-CU bandwidth.
extern "C" __global__ void __launch_bounds__(256)
snn_replay(const float* __restrict__ w,   const float* __restrict__ mu,
           const float* __restrict__ ic,  const float* __restrict__ u_re,
           float* __restrict__ out,
           const int* __restrict__ ws_eidx, const int* __restrict__ ws_cnt,
           const float* __restrict__ ws_snap)
{
#pragma clang fp contract(off)
    const int c = blockIdx.x >> 3;                       // chunk
    const int n = ((blockIdx.x & 7) << 8) + threadIdx.x; // neuron
    const float dt = 1.0f / 4096.0f;
    const float mu1 = mu[0], mu2 = mu[1];

    float* ys  = out;
    float* yev = out + (size_t)T_ * N_ * 3 + MAXSP;
    float* et  = yev + (size_t)MAXSP * N_ * 3;

    const float* sp = ws_snap + (size_t)c * 3 * N_;
    float v  = sp[n];
    float ii = sp[N_ + n];
    float ss = sp[2 * N_ + n];
    int cnt = ws_cnt[c];

    const int t0 = c << 8;
    const float* icp = ic + (size_t)t0 * N_ + n;
    const float* up  = u_re + (size_t)t0 * N_ + n;
    float* yr = ys + ((size_t)t0 * N_ + n) * 3;

    for (int k = 0; k < CHUNK; ++k) {
        const int t = t0 + k;
        const int e = ws_eidx[t];          // uniform scalar load
        const float icv = icp[0];

        float v1 = v + dt * (mu1 * ((ii + icv) - v));
        float i1 = ii + dt * ((-mu2) * ii);
        float spv = fmaxf(v, 0.0f) + __logf(1.0f + __expf(-fabsf(v)));
        float s1 = ss + dt * spv;
        bool m = (s1 >= 0.0f);

        if (e >= 0) {                      // event step (uniform branch)
            float wv_ = w[(size_t)e * N_ + n];
            float uu  = up[0];
            if (cnt < MAXSP) {             // record pre-transition state
                float* ye = yev + ((size_t)cnt * N_ + n) * 3;
                ye[0] = v1; ye[1] = i1; ye[2] = s1;
                et[(size_t)cnt * N_ + n] = m ? 1.0f : 0.0f;
                cnt++;
            }
            v  = m ? (v1 - 1.0f) : v1;
            ii = i1 + wv_;
            ss = m ? (__logf(uu) - 0.01f) : s1;
        } else {
            v = v1; ii = i1; ss = s1;
        }

        yr[0] = v; yr[1] = ii; yr[2] = ss;

        icp += N_; up += N_; yr += (size_t)3 * N_;
    }
}

extern "C" void kernel_launch(void* const* d_in, const int* in_sizes, int n_in,
                              void* d_out, int out_size, void* d_ws, size_t ws_size,
                              hipStream_t stream) {
    const float* w      = (const float*)d_in[0];
    const float* mu     = (const float*)d_in[1];
    const float* v0     = (const float*)d_in[2];
    const float* i0     = (const float*)d_in[3];
    const float* ic     = (const float*)d_in[4];
    const float* u_init = (const float*)d_in[5];
    const float* u_re   = (const float*)d_in[6];
    float* out = (float*)d_out;

    char* ws = (char*)d_ws;
    int*   ws_eidx = (int*)(ws + WS_EIDX_OFF);
    int*   ws_cnt  = (int*)(ws + WS_CNT_OFF);
    float* ws_snap = (float*)(ws + WS_SNAP_OFF);

    const size_t tail = (size_t)MAXSP + (size_t)MAXSP * N_ * 3 + (size_t)MAXSP * N_;
    int blocks = (int)((tail + 255) / 256);
    snn_init_tail<<<blocks, 256, 0, stream>>>(out);

    snn_scan<<<1, 1024, 0, stream>>>(w, mu, v0, i0, ic, u_init, u_re,
                                     out, ws_eidx, ws_cnt, ws_snap);

    snn_replay<<<NCHUNK * 8, 256, 0, stream>>>(w, mu, ic, u_re, out,
                                               ws_eidx, ws_cnt, ws_snap);
}

// Round 4
// 4297.342 us; speedup vs baseline: 2.5471x; 1.0028x over previous
//
#include <hip/hip_runtime.h>
#include <cmath>
#include <climits>

#define N_ 2048
#define T_ 4096
#define MAXSP 256
#define CHUNK 256
#define NCHUNK (T_ / CHUNK)   // 16

// ---------------- workspace layout (d_ws) ----------------
#define WS_EIDX_OFF   0
#define WS_CNT_OFF    (T_ * 4)
#define WS_SNAP_OFF   (T_ * 4 + NCHUNK * 4)

__device__ __forceinline__ int imin(int a, int b) { return a < b ? a : b; }

// Raw workgroup barrier with LDS visibility only: s_waitcnt lgkmcnt(0) +
// s_barrier. Crucially does NOT drain vmcnt, so global prefetch loads
// (ic, u_re, w-row) stay in flight across the per-step barrier.
// __syncthreads() would emit s_waitcnt vmcnt(0) with globals pending.
__device__ __forceinline__ void lds_barrier() {
    asm volatile("s_waitcnt lgkmcnt(0)\n\ts_barrier" ::: "memory");
}

// Fill tevents/yevents with +inf, event_types with 0.
__global__ void snn_init_tail(float* __restrict__ out) {
    const size_t base    = (size_t)T_ * N_ * 3;
    const size_t inf_cnt = (size_t)MAXSP + (size_t)MAXSP * N_ * 3;
    const size_t tot     = inf_cnt + (size_t)MAXSP * N_;
    size_t idx = (size_t)blockIdx.x * blockDim.x + threadIdx.x;
    if (idx < tot) {
        out[base + idx] = (idx < inf_cnt) ? __builtin_inff() : 0.0f;
    }
}

// ---------------- Kernel A: sequential scan (1 WG, software-pipelined) ----
// Per-lane v,s transitions depend only on the lane's own mask; the global
// eidx couples lanes only through i, which affects masks two steps later.
// So: compute mask[k] BEFORE waiting on the pending w[k-1] row load.
extern "C" __global__ void __launch_bounds__(1024)
snn_scan(const float* __restrict__ w,   const float* __restrict__ mu,
         const float* __restrict__ v0,  const float* __restrict__ i0,
         const float* __restrict__ ic,  const float* __restrict__ u_init,
         const float* __restrict__ u_re, float* __restrict__ out,
         int* __restrict__ ws_eidx, int* __restrict__ ws_cnt,
         float* __restrict__ ws_snap)
{
#pragma clang fp contract(off)
    const int tid = threadIdx.x;
    const int n0  = tid * 2;             // two adjacent neurons -> float2
    const int wv  = tid >> 6, lane = tid & 63;
    const float dt = 1.0f / 4096.0f;     // exact: 2^-12
    const float mu1 = mu[0], mu2 = mu[1];

    float* tev = out + (size_t)T_ * N_ * 3;
    float* nsp = tev + MAXSP + (size_t)MAXSP * N_ * 3 + (size_t)MAXSP * N_;

    // pipeline state: (vc,sc) = post-transition state of step k-1;
    // i1p = pre-w i1 of step k-1; (evp,w2) = pending event/w-row load.
    float vc0, vc1, sc0, sc1, i1p0, i1p1;
    { float2 a = *(const float2*)(v0 + n0); vc0 = a.x; vc1 = a.y; }
    { float2 a = *(const float2*)(i0 + n0); i1p0 = a.x; i1p1 = a.y; }
    { float2 a = *(const float2*)(u_init + n0);
      sc0 = logf(a.x) - 0.01f; sc1 = logf(a.y) - 0.01f; }  // one-time precise

    bool evp = false;
    float2 w2 = make_float2(0.0f, 0.0f);

    __shared__ __align__(16) int red[2][16];

    // 2-deep prefetch pipeline for ic and u_re
    const float* icp = ic + n0;
    const float* up  = u_re + n0;
    float2 icA = *(const float2*)(icp);
    float2 icB = *(const float2*)(icp + N_);
    float2 uA  = *(const float2*)(up);
    float2 uB  = *(const float2*)(up + N_);
    icp += 2 * N_; up += 2 * N_;

    int cnt = 0;
#pragma unroll 2
    for (int k = 0; k < T_; ++k) {
        // [1] mask_k from (vc, sc) — independent of pending w-row
        float sp0 = fmaxf(vc0, 0.0f) + __logf(1.0f + __expf(-fabsf(vc0)));
        float sp1 = fmaxf(vc1, 0.0f) + __logf(1.0f + __expf(-fabsf(vc1)));
        float s1_0 = sc0 + dt * sp0;
        float s1_1 = sc1 + dt * sp1;
        bool m0 = (s1_0 >= 0.0f), m1 = (s1_1 >= 0.0f);

        // wave candidate: first lane with any spike holds the min neuron
        int c_loc = m0 ? n0 : (m1 ? (n0 + 1) : INT_MAX);
        unsigned long long b = __ballot(m0 || m1);
        int cand = INT_MAX;
        if (b) {
            int fl = __ffsll((long long)b) - 1;
            cand = __shfl(c_loc, fl);
        }

        // [2] cross-wave min reduction (double-buffered slot, raw barrier)
        if (lane == 0) red[k & 1][wv] = cand;
        lds_barrier();
        const int4* r4 = (const int4*)red[k & 1];
        int4 a4 = r4[0], b4 = r4[1], c4 = r4[2], d4 = r4[3];
        int e01 = imin(imin(a4.x, a4.y), imin(a4.z, a4.w));
        int e23 = imin(imin(b4.x, b4.y), imin(b4.z, b4.w));
        int e45 = imin(imin(c4.x, c4.y), imin(c4.z, c4.w));
        int e67 = imin(imin(d4.x, d4.y), imin(d4.z, d4.w));
        int eidx = imin(imin(e01, e23), imin(e45, e67));
        eidx = __builtin_amdgcn_readfirstlane(eidx);   // scalarize

        // [3] finalize i_{k-1}: waits the pending w[k-1] load (covered by
        // the softplus chain + ballot + barrier above)
        float ip0 = i1p0, ip1 = i1p1;
        if (evp) { ip0 += w2.x; ip1 += w2.y; }

        // chunk snapshot: state after step k-1 (= chunk-start state)
        if ((k & (CHUNK - 1)) == 0) {
            const int c = k >> 8;
            float* sp = ws_snap + (size_t)c * 3 * N_;
            *(float2*)(sp + n0)          = make_float2(vc0, vc1);
            *(float2*)(sp + N_ + n0)     = make_float2(ip0, ip1);
            *(float2*)(sp + 2 * N_ + n0) = make_float2(sc0, sc1);
            if (tid == 0) ws_cnt[c] = cnt;
        }

        // [4] Euler for step k — reference op order, no FMA contraction
        float v1_0 = vc0 + dt * (mu1 * ((ip0 + icA.x) - vc0));
        float v1_1 = vc1 + dt * (mu1 * ((ip1 + icA.y) - vc1));
        i1p0 = ip0 + dt * ((-mu2) * ip0);
        i1p1 = ip1 + dt * ((-mu2) * ip1);

        // [5]+[6] event handling + per-lane transitions
        evp = (eidx != INT_MAX);
        vc0 = m0 ? (v1_0 - 1.0f) : v1_0;
        vc1 = m1 ? (v1_1 - 1.0f) : v1_1;
        if (evp) {
            // issue next pending w-row load (waited next iteration at [3])
            w2 = *(const float2*)(w + (size_t)eidx * N_ + n0);
            sc0 = m0 ? (__logf(uA.x) - 0.01f) : s1_0;
            sc1 = m1 ? (__logf(uA.y) - 0.01f) : s1_1;
            if (tid == 0) {
                ws_eidx[k] = eidx;
                if (cnt < MAXSP) tev[cnt] = (float)(k + 1) * dt;
            }
            if (cnt < MAXSP) cnt++;
        } else {
            sc0 = s1_0; sc1 = s1_1;
            if (tid == 0) ws_eidx[k] = -1;
        }

        // [7] advance 2-deep prefetch
        icA = icB; uA = uB;
        if (k + 2 < T_) {
            icB = *(const float2*)icp;
            uB  = *(const float2*)up;
            icp += N_; up += N_;
        }
    }

    if (tid == 0) nsp[0] = (float)cnt;
}

// ---------------- Kernel B: parallel replay ----------------
extern "C" __global__ void __launch_bounds__(256)
snn_replay(const float* __restrict__ w,   const float* __restrict__ mu,
           const float* __restrict__ ic,  const float* __restrict__ u_re,
           float* __restrict__ out,
           const int* __restrict__ ws_eidx, const int* __restrict__ ws_cnt,
           const float* __restrict__ ws_snap)
{
#pragma clang fp contract(off)
    const int c = blockIdx.x >> 3;                       // chunk
    const int n = ((blockIdx.x & 7) << 8) + threadIdx.x; // neuron
    const float dt = 1.0f / 4096.0f;
    const float mu1 = mu[0], mu2 = mu[1];

    float* ys  = out;
    float* yev = out + (size_t)T_ * N_ * 3 + MAXSP;
    float* et  = yev + (size_t)MAXSP * N_ * 3;

    const float* sp = ws_snap + (size_t)c * 3 * N_;
    float v  = sp[n];
    float ii = sp[N_ + n];
    float ss = sp[2 * N_ + n];
    int cnt = ws_cnt[c];

    const int t0 = c << 8;
    const float* icp = ic + (size_t)t0 * N_ + n;
    const float* up  = u_re + (size_t)t0 * N_ + n;
    float* yr = ys + ((size_t)t0 * N_ + n) * 3;

    for (int k = 0; k < CHUNK; ++k) {
        const int t = t0 + k;
        const int e = ws_eidx[t];          // uniform scalar load
        const float icv = icp[0];

        float v1 = v + dt * (mu1 * ((ii + icv) - v));
        float i1 = ii + dt * ((-mu2) * ii);
        float spv = fmaxf(v, 0.0f) + __logf(1.0f + __expf(-fabsf(v)));
        float s1 = ss + dt * spv;
        bool m = (s1 >= 0.0f);

        if (e >= 0) {                      // event step (uniform branch)
            float wv_ = w[(size_t)e * N_ + n];
            float uu  = up[0];
            if (cnt < MAXSP) {             // record pre-transition state
                float* ye = yev + ((size_t)cnt * N_ + n) * 3;
                ye[0] = v1; ye[1] = i1; ye[2] = s1;
                et[(size_t)cnt * N_ + n] = m ? 1.0f : 0.0f;
                cnt++;
            }
            v  = m ? (v1 - 1.0f) : v1;
            ii = i1 + wv_;
            ss = m ? (__logf(uu) - 0.01f) : s1;
        } else {
            v = v1; ii = i1; ss = s1;
        }

        yr[0] = v; yr[1] = ii; yr[2] = ss;

        icp += N_; up += N_; yr += (size_t)3 * N_;
    }
}

extern "C" void kernel_launch(void* const* d_in, const int* in_sizes, int n_in,
                              void* d_out, int out_size, void* d_ws, size_t ws_size,
                              hipStream_t stream) {
    const float* w      = (const float*)d_in[0];
    const float* mu     = (const float*)d_in[1];
    const float* v0     = (const float*)d_in[2];
    const float* i0     = (const float*)d_in[3];
    const float* ic     = (const float*)d_in[4];
    const float* u_init = (const float*)d_in[5];
    const float* u_re   = (const float*)d_in[6];
    float* out = (float*)d_out;

    char* ws = (char*)d_ws;
    int*   ws_eidx = (int*)(ws + WS_EIDX_OFF);
    int*   ws_cnt  = (int*)(ws + WS_CNT_OFF);
    float* ws_snap = (float*)(ws + WS_SNAP_OFF);

    const size_t tail = (size_t)MAXSP + (size_t)MAXSP * N_ * 3 + (size_t)MAXSP * N_;
    int blocks = (int)((tail + 255) / 256);
    snn_init_tail<<<blocks, 256, 0, stream>>>(out);

    snn_scan<<<1, 1024, 0, stream>>>(w, mu, v0, i0, ic, u_init, u_re,
                                     out, ws_eidx, ws_cnt, ws_snap);

    snn_replay<<<NCHUNK * 8, 256, 0, stream>>>(w, mu, ic, u_re, out,
                                               ws_eidx, ws_cnt, ws_snap);
}

// Round 5
// 4019.220 us; speedup vs baseline: 2.7234x; 1.0692x over previous
//
#include <hip/hip_runtime.h>
#include <cmath>
#include <climits>

#define N_ 2048
#define T_ 4096
#define MAXSP 256
#define CHUNK 256
#define NCHUNK (T_ / CHUNK)   // 16

// ---------------- workspace layout (d_ws) ----------------
#define WS_EIDX_OFF   0
#define WS_CNT_OFF    (T_ * 4)
#define WS_SNAP_OFF   (T_ * 4 + NCHUNK * 4)

typedef float f2 __attribute__((ext_vector_type(2)));

__device__ __forceinline__ int imin(int a, int b) { return a < b ? a : b; }

// Raw workgroup barrier with LDS visibility only (no vmcnt drain):
// global prefetches (ic, u_re, w-row) stay in flight across it.
__device__ __forceinline__ void lds_barrier() {
    asm volatile("s_waitcnt lgkmcnt(0)\n\ts_barrier" ::: "memory");
}

// Fill tevents/yevents with +inf, event_types with 0.
__global__ void snn_init_tail(float* __restrict__ out) {
    const size_t base    = (size_t)T_ * N_ * 3;
    const size_t inf_cnt = (size_t)MAXSP + (size_t)MAXSP * N_ * 3;
    const size_t tot     = inf_cnt + (size_t)MAXSP * N_;
    size_t idx = (size_t)blockIdx.x * blockDim.x + threadIdx.x;
    if (idx < tot) {
        out[base + idx] = (idx < inf_cnt) ? __builtin_inff() : 0.0f;
    }
}

// ---------------- Kernel A: sequential scan (1 WG, software-pipelined) ----
extern "C" __global__ void __launch_bounds__(1024)
snn_scan(const float* __restrict__ w,   const float* __restrict__ mu,
         const float* __restrict__ v0,  const float* __restrict__ i0,
         const float* __restrict__ ic,  const float* __restrict__ u_init,
         const float* __restrict__ u_re, float* __restrict__ out,
         int* __restrict__ ws_eidx, int* __restrict__ ws_cnt,
         float* __restrict__ ws_snap)
{
#pragma clang fp contract(off)
    const int tid = threadIdx.x;
    const int n0  = tid * 2;             // two adjacent neurons -> f2 ops
    const int wv  = tid >> 6, lane = tid & 63;
    const float dt = 1.0f / 4096.0f;     // exact: 2^-12
    const float mu1 = mu[0], mu2 = mu[1];

    float* tev = out + (size_t)T_ * N_ * 3;
    float* nsp = tev + MAXSP + (size_t)MAXSP * N_ * 3 + (size_t)MAXSP * N_;

    // pipeline state: (vc,sc) = post-transition state of step k-1;
    // i1p = pre-w i1 of step k-1; (evp,w2) = pending event / w-row load.
    f2 vc, sc, i1p;
    vc  = *(const f2*)(v0 + n0);
    i1p = *(const f2*)(i0 + n0);
    { f2 a = *(const f2*)(u_init + n0);
      sc.x = logf(a.x) - 0.01f; sc.y = logf(a.y) - 0.01f; }  // one-time precise

    bool evp = false;
    f2 w2; w2.x = 0.0f; w2.y = 0.0f;

    __shared__ __align__(16) int red[2][16];

    // 2-deep prefetch pipeline for ic and u_re
    const float* icp = ic + n0;
    const float* up  = u_re + n0;
    f2 icA = *(const f2*)(icp);
    f2 icB = *(const f2*)(icp + N_);
    f2 uA  = *(const f2*)(up);
    f2 uB  = *(const f2*)(up + N_);
    icp += 2 * N_; up += 2 * N_;

    int cnt = 0;
#pragma unroll 2
    for (int k = 0; k < T_; ++k) {
        // [1] softplus + mask_k from (vc, sc) — independent of pending w-row.
        // Fast path: for v >= 16, fmax(v,0)+__logf(1+__expf(-v)) rounds to
        // EXACTLY v in fp32 (correction < half-ulp), so both paths are
        // bit-identical; take the transcendental path only if any lane
        // in the wave has v < 16 (wave-uniform branch).
        f2 sp;
        bool slow = (fminf(vc.x, vc.y) < 16.0f);
        if (__ballot(slow)) {
            sp.x = fmaxf(vc.x, 0.0f) + __logf(1.0f + __expf(-fabsf(vc.x)));
            sp.y = fmaxf(vc.y, 0.0f) + __logf(1.0f + __expf(-fabsf(vc.y)));
        } else {
            sp = vc;
        }
        f2 s1 = sc + dt * sp;
        bool m0 = (s1.x >= 0.0f), m1 = (s1.y >= 0.0f);

        // wave candidate: first lane with any spike holds the min neuron
        int c_loc = m0 ? n0 : (m1 ? (n0 + 1) : INT_MAX);
        unsigned long long b = __ballot(m0 || m1);
        int cand = INT_MAX;
        if (b) {
            int fl = __ffsll((long long)b) - 1;
            cand = __shfl(c_loc, fl);
        }

        // [2] cross-wave min reduction (double-buffered slot, raw barrier)
        if (lane == 0) red[k & 1][wv] = cand;
        lds_barrier();
        const int4* r4 = (const int4*)red[k & 1];
        int4 a4 = r4[0], b4 = r4[1], c4 = r4[2], d4 = r4[3];
        int e01 = imin(imin(a4.x, a4.y), imin(a4.z, a4.w));
        int e23 = imin(imin(b4.x, b4.y), imin(b4.z, b4.w));
        int e45 = imin(imin(c4.x, c4.y), imin(c4.z, c4.w));
        int e67 = imin(imin(d4.x, d4.y), imin(d4.z, d4.w));
        int eidx = imin(imin(e01, e23), imin(e45, e67));
        eidx = __builtin_amdgcn_readfirstlane(eidx);   // scalarize

        // [3] finalize i_{k-1}: waits the pending w[k-1] row load
        f2 ip = i1p;
        if (evp) ip += w2;

        // chunk snapshot: state after step k-1 (= chunk-start state)
        if ((k & (CHUNK - 1)) == 0) {
            const int c = k >> 8;
            float* spn = ws_snap + (size_t)c * 3 * N_;
            *(f2*)(spn + n0)          = vc;
            *(f2*)(spn + N_ + n0)     = ip;
            *(f2*)(spn + 2 * N_ + n0) = sc;
            if (tid == 0) ws_cnt[c] = cnt;
        }

        // [4] Euler for step k — reference op order, no FMA contraction
        f2 v1 = vc + dt * (mu1 * ((ip + icA) - vc));
        i1p   = ip + dt * ((-mu2) * ip);

        // [5]+[6] event handling + per-lane transitions
        evp = (eidx != INT_MAX);
        vc.x = m0 ? (v1.x - 1.0f) : v1.x;
        vc.y = m1 ? (v1.y - 1.0f) : v1.y;
        if (evp) {
            // issue next pending w-row load (waited next iteration at [3])
            w2 = *(const f2*)(w + (size_t)eidx * N_ + n0);
            sc.x = m0 ? (__logf(uA.x) - 0.01f) : s1.x;
            sc.y = m1 ? (__logf(uA.y) - 0.01f) : s1.y;
            if (tid == 0) {
                ws_eidx[k] = eidx;
                if (cnt < MAXSP) tev[cnt] = (float)(k + 1) * dt;
            }
            if (cnt < MAXSP) cnt++;
        } else {
            sc = s1;
            if (tid == 0) ws_eidx[k] = -1;
        }

        // [7] advance 2-deep prefetch
        icA = icB; uA = uB;
        if (k + 2 < T_) {
            icB = *(const f2*)icp;
            uB  = *(const f2*)up;
            icp += N_; up += N_;
        }
    }

    if (tid == 0) nsp[0] = (float)cnt;
}

// ---------------- Kernel B: parallel replay ----------------
extern "C" __global__ void __launch_bounds__(256)
snn_replay(const float* __restrict__ w,   const float* __restrict__ mu,
           const float* __restrict__ ic,  const float* __restrict__ u_re,
           float* __restrict__ out,
           const int* __restrict__ ws_eidx, const int* __restrict__ ws_cnt,
           const float* __restrict__ ws_snap)
{
#pragma clang fp contract(off)
    const int c = blockIdx.x >> 3;                       // chunk
    const int n = ((blockIdx.x & 7) << 8) + threadIdx.x; // neuron
    const float dt = 1.0f / 4096.0f;
    const float mu1 = mu[0], mu2 = mu[1];

    float* ys  = out;
    float* yev = out + (size_t)T_ * N_ * 3 + MAXSP;
    float* et  = yev + (size_t)MAXSP * N_ * 3;

    const float* sp = ws_snap + (size_t)c * 3 * N_;
    float v  = sp[n];
    float ii = sp[N_ + n];
    float ss = sp[2 * N_ + n];
    int cnt = ws_cnt[c];

    const int t0 = c << 8;
    const float* icp = ic + (size_t)t0 * N_ + n;
    const float* up  = u_re + (size_t)t0 * N_ + n;
    float* yr = ys + ((size_t)t0 * N_ + n) * 3;

    for (int k = 0; k < CHUNK; ++k) {
        const int t = t0 + k;
        const int e = ws_eidx[t];          // uniform scalar load
        const float icv = icp[0];

        float v1 = v + dt * (mu1 * ((ii + icv) - v));
        float i1 = ii + dt * ((-mu2) * ii);
        // same bit-exact fast/slow softplus as the scan
        float spv;
        if (__ballot(v < 16.0f)) {
            spv = fmaxf(v, 0.0f) + __logf(1.0f + __expf(-fabsf(v)));
        } else {
            spv = v;
        }
        float s1 = ss + dt * spv;
        bool m = (s1 >= 0.0f);

        if (e >= 0) {                      // event step (uniform branch)
            float wv_ = w[(size_t)e * N_ + n];
            float uu  = up[0];
            if (cnt < MAXSP) {             // record pre-transition state
                float* ye = yev + ((size_t)cnt * N_ + n) * 3;
                ye[0] = v1; ye[1] = i1; ye[2] = s1;
                et[(size_t)cnt * N_ + n] = m ? 1.0f : 0.0f;
                cnt++;
            }
            v  = m ? (v1 - 1.0f) : v1;
            ii = i1 + wv_;
            ss = m ? (__logf(uu) - 0.01f) : s1;
        } else {
            v = v1; ii = i1; ss = s1;
        }

        yr[0] = v; yr[1] = ii; yr[2] = ss;

        icp += N_; up += N_; yr += (size_t)3 * N_;
    }
}

extern "C" void kernel_launch(void* const* d_in, const int* in_sizes, int n_in,
                              void* d_out, int out_size, void* d_ws, size_t ws_size,
                              hipStream_t stream) {
    const float* w      = (const float*)d_in[0];
    const float* mu     = (const float*)d_in[1];
    const float* v0     = (const float*)d_in[2];
    const float* i0     = (const float*)d_in[3];
    const float* ic     = (const float*)d_in[4];
    const float* u_init = (const float*)d_in[5];
    const float* u_re   = (const float*)d_in[6];
    float* out = (float*)d_out;

    char* ws = (char*)d_ws;
    int*   ws_eidx = (int*)(ws + WS_EIDX_OFF);
    int*   ws_cnt  = (int*)(ws + WS_CNT_OFF);
    float* ws_snap = (float*)(ws + WS_SNAP_OFF);

    const size_t tail = (size_t)MAXSP + (size_t)MAXSP * N_ * 3 + (size_t)MAXSP * N_;
    int blocks = (int)((tail + 255) / 256);
    snn_init_tail<<<blocks, 256, 0, stream>>>(out);

    snn_scan<<<1, 1024, 0, stream>>>(w, mu, v0, i0, ic, u_init, u_re,
                                     out, ws_eidx, ws_cnt, ws_snap);

    snn_replay<<<NCHUNK * 8, 256, 0, stream>>>(w, mu, ic, u_re, out,
                                               ws_eidx, ws_cnt, ws_snap);
}